// Round 2
// baseline (1899.698 us; speedup 1.0000x reference)
//
#include <hip/hip_runtime.h>

typedef unsigned short u16;
typedef __bf16 bf16x8 __attribute__((ext_vector_type(8)));
typedef float f32x4 __attribute__((ext_vector_type(4)));

__device__ __forceinline__ u16 f2bf(float f) {
    union { float f; unsigned u; } v; v.f = f;
    unsigned r = v.u + 0x7FFFu + ((v.u >> 16) & 1u);   // RNE
    return (u16)(r >> 16);
}

// ---------------- f32 -> bf16 cast (n % 4 == 0) ----------------
__global__ void cast_f32_bf16(const float* __restrict__ src, u16* __restrict__ dst, long n4) {
    long i = (long)blockIdx.x * blockDim.x + threadIdx.x;
    long stride = (long)gridDim.x * blockDim.x;
    for (; i < n4; i += stride) {
        float4 f = reinterpret_cast<const float4*>(src)[i];
        ushort4 o;
        o.x = f2bf(f.x); o.y = f2bf(f.y); o.z = f2bf(f.z); o.w = f2bf(f.w);
        reinterpret_cast<ushort4*>(dst)[i] = o;
    }
}

// ---------------- token + positional embedding ----------------
__global__ __launch_bounds__(256) void embed_kernel(
    const int* __restrict__ labels, const float* __restrict__ tok_emb,
    const float* __restrict__ pos_emb, float* __restrict__ x, u16* __restrict__ xb)
{
    int r = blockIdx.x;                 // 0..8191 = b*512+t
    int b = r >> 9, t = r & 511;
    int tok = labels[b * 513 + t];      // labels[:, :-1]
    const float* te = tok_emb + (long)tok * 768;
    const float* pe = pos_emb + (long)t * 768;
    float* xo  = x  + (long)r * 768;
    u16*   xo2 = xb + (long)r * 768;
#pragma unroll
    for (int j = 0; j < 3; j++) {
        int d = threadIdx.x + j * 256;
        float v = te[d] + pe[d];
        xo[d] = v;
        xo2[d] = f2bf(v);
    }
}

// ---------------- bf16 MFMA GEMM: C = A[M,K] * W[N,K]^T + bias ----------------
// 64x64 tile, BK=32, 4 waves (2x2), each wave 32x32 = 2x2 16x16 fragments.
// batched via blockIdx.z: off = (z/NH)*s?b + (z%NH)*s?h
template<int OB, int RELU>
__global__ __launch_bounds__(256) void gemm_bt(
    const u16* __restrict__ A, int lda, long sAb, long sAh,
    const u16* __restrict__ W, int ldw, long sWb, long sWh,
    const float* __restrict__ bias,
    void* __restrict__ C, int ldc, long sCb, long sCh,
    int M, int N, int K, int NH)
{
    __shared__ __align__(16) u16 As[64][40];   // +8 pad: breaks pow2 bank stride
    __shared__ __align__(16) u16 Bs[64][40];
    int z = blockIdx.z, zb = z / NH, zh = z % NH;
    const u16* Ap = A + (long)zb * sAb + (long)zh * sAh;
    const u16* Wp = W + (long)zb * sWb + (long)zh * sWh;
    long coff = (long)zb * sCb + (long)zh * sCh;
    int m0 = blockIdx.y * 64, n0 = blockIdx.x * 64;
    int tid = threadIdx.x;
    int lrow = tid >> 2;              // 0..63
    int lcb = (tid & 3) * 8;          // 0,8,16,24
    int wid = tid >> 6, lane = tid & 63;
    int wr = (wid >> 1) * 32, wc = (wid & 1) * 32;
    int fr = lane & 15, fk = (lane >> 4) * 8;

    f32x4 zero4 = {0.f, 0.f, 0.f, 0.f};
    f32x4 acc00 = zero4, acc01 = zero4, acc10 = zero4, acc11 = zero4;

    int aRow = m0 + lrow; bool aOK = aRow < M;
    int wRow = n0 + lrow; bool wOK = wRow < N;
    const u16* aP = Ap + (long)aRow * lda + lcb;
    const u16* wP = Wp + (long)wRow * ldw + lcb;
    uint4 zz = {0u, 0u, 0u, 0u};

    for (int k0 = 0; k0 < K; k0 += 32) {
        uint4 av = zz, wv = zz;
        if (aOK) av = *reinterpret_cast<const uint4*>(aP + k0);
        if (wOK) wv = *reinterpret_cast<const uint4*>(wP + k0);
        __syncthreads();
        *reinterpret_cast<uint4*>(&As[lrow][lcb]) = av;
        *reinterpret_cast<uint4*>(&Bs[lrow][lcb]) = wv;
        __syncthreads();
        // A frag: row = lane&15, k = (lane>>4)*8 + j (8 contiguous bf16)
        bf16x8 a0 = *reinterpret_cast<const bf16x8*>(&As[wr + fr][fk]);
        bf16x8 a1 = *reinterpret_cast<const bf16x8*>(&As[wr + 16 + fr][fk]);
        bf16x8 b0 = *reinterpret_cast<const bf16x8*>(&Bs[wc + fr][fk]);
        bf16x8 b1 = *reinterpret_cast<const bf16x8*>(&Bs[wc + 16 + fr][fk]);
        acc00 = __builtin_amdgcn_mfma_f32_16x16x32_bf16(a0, b0, acc00, 0, 0, 0);
        acc01 = __builtin_amdgcn_mfma_f32_16x16x32_bf16(a0, b1, acc01, 0, 0, 0);
        acc10 = __builtin_amdgcn_mfma_f32_16x16x32_bf16(a1, b0, acc10, 0, 0, 0);
        acc11 = __builtin_amdgcn_mfma_f32_16x16x32_bf16(a1, b1, acc11, 0, 0, 0);
    }

    // C/D layout (m89/m91 verified): col = lane&15, row = (lane>>4)*4 + reg
    int crow = (lane >> 4) * 4;
    f32x4 accs[2][2] = {{acc00, acc01}, {acc10, acc11}};
#pragma unroll
    for (int fm = 0; fm < 2; fm++) {
#pragma unroll
        for (int fn = 0; fn < 2; fn++) {
            int col = n0 + wc + fn * 16 + fr;
            if (col >= N) continue;
            float bv = bias ? bias[col] : 0.f;
#pragma unroll
            for (int rr = 0; rr < 4; rr++) {
                int row = m0 + wr + fm * 16 + crow + rr;
                if (row >= M) continue;
                float v = accs[fm][fn][rr] + bv;
                if (RELU) v = fmaxf(v, 0.f);
                long idx = coff + (long)row * ldc + col;
                if (OB) ((u16*)C)[idx] = f2bf(v);
                else    ((float*)C)[idx] = v;
            }
        }
    }
}

// ---------------- V transpose with zero-pad: VT[z][d][k] = V[k][d], k>=rowsIn -> 0 ----------------
__global__ __launch_bounds__(256) void transpose_pad(
    const u16* __restrict__ V, long sVb, long sVh, int ldv, int NH,
    u16* __restrict__ VT, long sVT, int rowsIn, int Kp)
{
    __shared__ u16 tile[32][33];
    int z = blockIdx.z, zb = z / NH, zh = z % NH;
    const u16* Vp = V + (long)zb * sVb + (long)zh * sVh;
    int k0 = blockIdx.x * 32, d0 = blockIdx.y * 32;
#pragma unroll
    for (int i = 0; i < 4; i++) {
        int k = k0 + threadIdx.y + i * 8;
        int d = d0 + threadIdx.x;
        tile[threadIdx.y + i * 8][threadIdx.x] = (k < rowsIn) ? Vp[(long)k * ldv + d] : (u16)0;
    }
    __syncthreads();
    u16* Op = VT + (long)z * sVT;
#pragma unroll
    for (int i = 0; i < 4; i++) {
        int d = d0 + threadIdx.y + i * 8;
        int k = k0 + threadIdx.x;
        Op[(long)d * Kp + k] = tile[threadIdx.x][threadIdx.y + i * 8];
    }
}

// ---------------- row softmax (optionally causal), f32 scores -> bf16 probs, zero-pad to ld_out ----------------
__global__ __launch_bounds__(256) void softmax_kernel(
    const float* __restrict__ S, u16* __restrict__ P,
    int qrows, int cols_in, int ld_out, float scale, int causal)
{
    __shared__ float red[4];
    int r = blockIdx.x;
    int q = r % qrows;
    const float* srow = S + (long)r * cols_in;
    u16* prow = P + (long)r * ld_out;
    int valid = causal ? (q + 1) : cols_in;
    int tid = threadIdx.x, lane = tid & 63, wid = tid >> 6;
    int c0 = tid, c1 = tid + 256;
    float v0 = -3e38f, v1 = -3e38f;
    if (c0 < valid) v0 = srow[c0] * scale;
    if (c1 < valid) v1 = srow[c1] * scale;
    float mx = fmaxf(v0, v1);
#pragma unroll
    for (int o = 32; o; o >>= 1) mx = fmaxf(mx, __shfl_down(mx, o, 64));
    if (lane == 0) red[wid] = mx;
    __syncthreads();
    mx = fmaxf(fmaxf(red[0], red[1]), fmaxf(red[2], red[3]));
    __syncthreads();
    float e0 = (c0 < valid) ? __expf(v0 - mx) : 0.f;
    float e1 = (c1 < valid) ? __expf(v1 - mx) : 0.f;
    float s = e0 + e1;
#pragma unroll
    for (int o = 32; o; o >>= 1) s += __shfl_down(s, o, 64);
    if (lane == 0) red[wid] = s;
    __syncthreads();
    s = red[0] + red[1] + red[2] + red[3];
    float inv = 1.f / s;
    if (c0 < ld_out) prow[c0] = f2bf(e0 * inv);
    if (c1 < ld_out) prow[c1] = f2bf(e1 * inv);
}

// ---------------- fused residual add + LayerNorm; writes f32 stream + bf16 copy ----------------
__global__ __launch_bounds__(256) void ln_kernel(
    const float* __restrict__ xin, const float* __restrict__ sub,
    const float* __restrict__ g, const float* __restrict__ bta,
    float* __restrict__ xout, u16* __restrict__ xb)
{
    __shared__ float red[4];
    long r = blockIdx.x;
    const float* a = xin + r * 768;
    const float* s2 = sub + r * 768;
    int tid = threadIdx.x, lane = tid & 63, wid = tid >> 6;
    float v[3];
    float sum = 0.f;
#pragma unroll
    for (int j = 0; j < 3; j++) { int d = tid + j * 256; v[j] = a[d] + s2[d]; sum += v[j]; }
#pragma unroll
    for (int o = 32; o; o >>= 1) sum += __shfl_down(sum, o, 64);
    if (lane == 0) red[wid] = sum;
    __syncthreads();
    float mean = (red[0] + red[1] + red[2] + red[3]) * (1.f / 768.f);
    __syncthreads();
    float vs = 0.f;
#pragma unroll
    for (int j = 0; j < 3; j++) { float t = v[j] - mean; vs += t * t; }
#pragma unroll
    for (int o = 32; o; o >>= 1) vs += __shfl_down(vs, o, 64);
    if (lane == 0) red[wid] = vs;
    __syncthreads();
    float var = (red[0] + red[1] + red[2] + red[3]) * (1.f / 768.f);
    float rstd = rsqrtf(var + 1e-5f);
#pragma unroll
    for (int j = 0; j < 3; j++) {
        int d = tid + j * 256;
        float y = (v[j] - mean) * rstd * g[d] + bta[d];
        xout[r * 768 + d] = y;
        xb[r * 768 + d] = f2bf(y);
    }
}

// ---------------- second output: labels[:, 1:] as FLOAT32 (d_out is float*) ----------------
__global__ void labels_out_kernel(const int* __restrict__ labels, float* __restrict__ out) {
    int i = blockIdx.x * 256 + threadIdx.x;
    if (i >= 8192) return;
    int b = i >> 9, t = i & 511;
    out[i] = (float)labels[b * 513 + t + 1];
}

// ---------------- host helpers ----------------
static void gemm_launch(hipStream_t st, bool outbf, bool relu,
    const u16* A, int lda, long sAb, long sAh,
    const u16* W, int ldw, long sWb, long sWh,
    const float* bias, void* C, int ldc, long sCb, long sCh,
    int M, int N, int K, int Z, int NH)
{
    dim3 g((N + 63) / 64, (M + 63) / 64, Z), b(256, 1, 1);
    if (outbf) {
        if (relu) gemm_bt<1,1><<<g,b,0,st>>>(A,lda,sAb,sAh,W,ldw,sWb,sWh,bias,C,ldc,sCb,sCh,M,N,K,NH);
        else      gemm_bt<1,0><<<g,b,0,st>>>(A,lda,sAb,sAh,W,ldw,sWb,sWh,bias,C,ldc,sCb,sCh,M,N,K,NH);
    } else {
        if (relu) gemm_bt<0,1><<<g,b,0,st>>>(A,lda,sAb,sAh,W,ldw,sWb,sWh,bias,C,ldc,sCb,sCh,M,N,K,NH);
        else      gemm_bt<0,0><<<g,b,0,st>>>(A,lda,sAb,sAh,W,ldw,sWb,sWh,bias,C,ldc,sCb,sCh,M,N,K,NH);
    }
}

extern "C" void kernel_launch(void* const* d_in, const int* in_sizes, int n_in,
                              void* d_out, int out_size, void* d_ws, size_t ws_size,
                              hipStream_t stream)
{
    const int*   labels = (const int*)  d_in[0];
    const float* vision = (const float*)d_in[1];
    const float* vpw    = (const float*)d_in[2];
    const float* vpb    = (const float*)d_in[3];
    const float* temb   = (const float*)d_in[4];
    const float* pemb   = (const float*)d_in[5];
    const float* saw    = (const float*)d_in[6];
    const float* sab    = (const float*)d_in[7];
    const float* saow   = (const float*)d_in[8];
    const float* saob   = (const float*)d_in[9];
    const float* caw    = (const float*)d_in[10];
    const float* cab    = (const float*)d_in[11];
    const float* caow   = (const float*)d_in[12];
    const float* caob   = (const float*)d_in[13];
    const float* ln1g   = (const float*)d_in[14];
    const float* ln1b   = (const float*)d_in[15];
    const float* ln2g   = (const float*)d_in[16];
    const float* ln2b   = (const float*)d_in[17];
    const float* ln3g   = (const float*)d_in[18];
    const float* ln3b   = (const float*)d_in[19];
    const float* f1w    = (const float*)d_in[20];
    const float* f1b    = (const float*)d_in[21];
    const float* f2w    = (const float*)d_in[22];
    const float* f2b    = (const float*)d_in[23];
    const float* ow     = (const float*)d_in[24];
    const float* ob     = (const float*)d_in[25];
    (void)in_sizes; (void)n_in; (void)out_size;

    // ---- workspace layout (~291 MB) ----
    char* p = (char*)d_ws;
    auto alloc = [&](long elems, int esz) -> char* {
        char* r = p; p += ((long)elems * esz + 255) & ~255L; return r;
    };
    u16* wb_vp  = (u16*)alloc(768L*768, 2);
    u16* wb_sa  = (u16*)alloc(3L*2304*768, 2);
    u16* wb_sao = (u16*)alloc(3L*768*768, 2);
    u16* wb_ca  = (u16*)alloc(3L*2304*768, 2);
    u16* wb_cao = (u16*)alloc(3L*768*768, 2);
    u16* wb_f1  = (u16*)alloc(3L*1024*768, 2);
    u16* wb_f2  = (u16*)alloc(3L*768*1024, 2);
    u16* wb_ow  = (u16*)alloc(10000L*768, 2);
    u16* vis_b  = (u16*)alloc(3152L*768, 2);
    u16* mem_b  = (u16*)alloc(3152L*768, 2);
    float* x    = (float*)alloc(8192L*768, 4);
    u16* xb     = (u16*)alloc(8192L*768, 2);
    u16* qkv    = (u16*)alloc(8192L*2304, 2);   // reused: {qkv} | {q_bf,kv_bf} | {h_bf}
    u16* q_bf   = qkv;
    u16* kv_bf  = qkv + 8192L*768;
    u16* h_bf   = qkv;
    float* sc   = (float*)alloc(64L*512*512, 4);
    u16* pr     = (u16*)alloc(64L*512*512, 2);
    u16* vt     = (u16*)alloc(64L*192*512, 2);
    u16* attn   = (u16*)alloc(8192L*768, 2);
    float* sub  = (float*)alloc(8192L*768, 4);
    if ((size_t)(p - (char*)d_ws) > ws_size) return;   // clean fail if ws too small

    auto cast = [&](const float* s, u16* d, long n) {
        long n4 = n >> 2;
        int blocks = (int)((n4 + 255) / 256); if (blocks > 4096) blocks = 4096;
        cast_f32_bf16<<<dim3(blocks), dim3(256), 0, stream>>>(s, d, n4);
    };
    cast(vpw,  wb_vp,  768L*768);
    cast(saw,  wb_sa,  3L*2304*768);
    cast(saow, wb_sao, 3L*768*768);
    cast(caw,  wb_ca,  3L*2304*768);
    cast(caow, wb_cao, 3L*768*768);
    cast(f1w,  wb_f1,  3L*1024*768);
    cast(f2w,  wb_f2,  3L*768*1024);
    cast(ow,   wb_ow,  10000L*768);
    cast(vision, vis_b, 3152L*768);

    embed_kernel<<<dim3(8192), dim3(256), 0, stream>>>(labels, temb, pemb, x, xb);

    // mem = vision @ vis_proj_w^T + b   (16*197=3152 rows)
    gemm_launch(stream, true, false, vis_b, 768, 0,0, wb_vp, 768, 0,0, vpb,
                mem_b, 768, 0,0, 3152, 768, 768, 1, 1);

    const float scale = 0.07216878364870323f;  // 1/sqrt(192)

    for (int l = 0; l < 3; l++) {
        // ======== self-attention ========
        const u16* Wsa = wb_sa + (long)l*2304*768;
        gemm_launch(stream, true, false, xb, 768, 0,0, Wsa, 768, 0,0, sab + l*2304,
                    qkv, 2304, 0,0, 8192, 2304, 768, 1, 1);
        transpose_pad<<<dim3(16,6,64), dim3(32,8), 0, stream>>>(
            qkv + 1536, 512L*2304, 192L, 2304, 4, vt, 192L*512, 512, 512);
        // scores = Q K^T  (batched over b,h: z = b*4+h)
        gemm_launch(stream, false, false, qkv, 2304, 512L*2304, 192, qkv + 768, 2304, 512L*2304, 192,
                    nullptr, sc, 512, 4L*512*512, 512L*512, 512, 512, 192, 64, 4);
        softmax_kernel<<<dim3(64*512), dim3(256), 0, stream>>>(sc, pr, 512, 512, 512, scale, 1);
        // O = P @ V  (W = V^T)
        gemm_launch(stream, true, false, pr, 512, 4L*512*512, 512L*512, vt, 512, 4L*192*512, 192L*512,
                    nullptr, attn, 768, 512L*768, 192, 512, 192, 512, 64, 4);
        gemm_launch(stream, false, false, attn, 768, 0,0, wb_sao + (long)l*768*768, 768, 0,0,
                    saob + l*768, sub, 768, 0,0, 8192, 768, 768, 1, 1);
        ln_kernel<<<dim3(8192), dim3(256), 0, stream>>>(x, sub, ln1g + l*768, ln1b + l*768, x, xb);

        // ======== cross-attention ========
        const u16* Wca = wb_ca + (long)l*2304*768;
        gemm_launch(stream, true, false, xb, 768, 0,0, Wca, 768, 0,0, cab + l*2304,
                    q_bf, 768, 0,0, 8192, 768, 768, 1, 1);
        gemm_launch(stream, true, false, mem_b, 768, 0,0, Wca + 768L*768, 768, 0,0, cab + l*2304 + 768,
                    kv_bf, 1536, 0,0, 3152, 1536, 768, 1, 1);
        transpose_pad<<<dim3(7,6,64), dim3(32,8), 0, stream>>>(
            kv_bf + 768, 197L*1536, 192L, 1536, 4, vt, 192L*224, 197, 224);
        gemm_launch(stream, false, false, q_bf, 768, 512L*768, 192, kv_bf, 1536, 197L*1536, 192,
                    nullptr, sc, 197, 4L*512*197, 512L*197, 512, 197, 192, 64, 4);
        softmax_kernel<<<dim3(64*512), dim3(256), 0, stream>>>(sc, pr, 512, 197, 224, scale, 0);
        gemm_launch(stream, true, false, pr, 224, 4L*512*224, 512L*224, vt, 224, 4L*192*224, 192L*224,
                    nullptr, attn, 768, 512L*768, 192, 512, 192, 224, 64, 4);
        gemm_launch(stream, false, false, attn, 768, 0,0, wb_cao + (long)l*768*768, 768, 0,0,
                    caob + l*768, sub, 768, 0,0, 8192, 768, 768, 1, 1);
        ln_kernel<<<dim3(8192), dim3(256), 0, stream>>>(x, sub, ln2g + l*768, ln2b + l*768, x, xb);

        // ======== feed-forward ========
        gemm_launch(stream, true, true, xb, 768, 0,0, wb_f1 + (long)l*1024*768, 768, 0,0,
                    f1b + l*1024, h_bf, 1024, 0,0, 8192, 1024, 768, 1, 1);
        gemm_launch(stream, false, false, h_bf, 1024, 0,0, wb_f2 + (long)l*768*1024, 1024, 0,0,
                    f2b + l*768, sub, 768, 0,0, 8192, 768, 1024, 1, 1);
        ln_kernel<<<dim3(8192), dim3(256), 0, stream>>>(x, sub, ln3g + l*768, ln3b + l*768, x, xb);
    }

    // vocab head -> d_out (FLOAT32 logits — d_out is float*)
    gemm_launch(stream, false, false, xb, 768, 0,0, wb_ow, 768, 0,0, ob,
                (float*)d_out, 10000, 0,0, 8192, 10000, 768, 1, 1);
    // second output: labels[:, 1:] as float32
    labels_out_kernel<<<dim3(32), dim3(256), 0, stream>>>(labels, (float*)d_out + 81920000L);
}

// Round 3
// 1854.474 us; speedup vs baseline: 1.0244x; 1.0244x over previous
//
#include <hip/hip_runtime.h>

typedef unsigned short u16;
typedef __bf16 bf16x8 __attribute__((ext_vector_type(8)));
typedef float f32x4 __attribute__((ext_vector_type(4)));

typedef __attribute__((address_space(3))) u16 lds_u16_t;
typedef __attribute__((address_space(1))) const u16 glb_u16_t;

__device__ __forceinline__ u16 f2bf(float f) {
    union { float f; unsigned u; } v; v.f = f;
    unsigned r = v.u + 0x7FFFu + ((v.u >> 16) & 1u);   // RNE
    return (u16)(r >> 16);
}

// ---------------- f32 -> bf16 cast (n % 4 == 0) ----------------
__global__ void cast_f32_bf16(const float* __restrict__ src, u16* __restrict__ dst, long n4) {
    long i = (long)blockIdx.x * blockDim.x + threadIdx.x;
    long stride = (long)gridDim.x * blockDim.x;
    for (; i < n4; i += stride) {
        float4 f = reinterpret_cast<const float4*>(src)[i];
        ushort4 o;
        o.x = f2bf(f.x); o.y = f2bf(f.y); o.z = f2bf(f.z); o.w = f2bf(f.w);
        reinterpret_cast<ushort4*>(dst)[i] = o;
    }
}

// ---------------- token + positional embedding ----------------
__global__ __launch_bounds__(256) void embed_kernel(
    const int* __restrict__ labels, const float* __restrict__ tok_emb,
    const float* __restrict__ pos_emb, float* __restrict__ x, u16* __restrict__ xb)
{
    int r = blockIdx.x;                 // 0..8191 = b*512+t
    int b = r >> 9, t = r & 511;
    int tok = labels[b * 513 + t];      // labels[:, :-1]
    const float* te = tok_emb + (long)tok * 768;
    const float* pe = pos_emb + (long)t * 768;
    float* xo  = x  + (long)r * 768;
    u16*   xo2 = xb + (long)r * 768;
#pragma unroll
    for (int j = 0; j < 3; j++) {
        int d = threadIdx.x + j * 256;
        float v = te[d] + pe[d];
        xo[d] = v;
        xo2[d] = f2bf(v);
    }
}

// ================= 128x128 MFMA GEMM (m97 structure): C = A[M,K] * W[N,K]^T + bias =================
// 4 waves (2x2), each wave a 64x64 sub-tile = 4x4 16x16x32 fragments.
// Staging via global_load_lds width=16 into LINEAR LDS [128][32] (wave-uniform base + lane*16).
// M/N edges handled by clamping source rows (garbage lands only in masked-out outputs). K % 32 == 0.
template<int OB, int RELU>
__global__ __launch_bounds__(256) void gemm128(
    const u16* __restrict__ A, int lda,
    const u16* __restrict__ W, int ldw,
    const float* __restrict__ bias,
    void* __restrict__ C, int ldc,
    int M, int N, int K)
{
    __shared__ __align__(16) u16 As[128 * 32];
    __shared__ __align__(16) u16 Bs[128 * 32];
    int m0 = blockIdx.y * 128, n0 = blockIdx.x * 128;
    int tid = threadIdx.x, wid = tid >> 6, lane = tid & 63;
    int wr = (wid >> 1) * 64, wc = (wid & 1) * 64;
    int fr = lane & 15, fk = (lane >> 4) * 8;

    // staging geometry: 8 chunks of 1KB per tile; wave w stages chunks {w, w+4}
    int li0 = wid * 64 + lane;          // 16B-unit linear index, pass 0
    int li1 = li0 + 256;                // pass 1
    int r0 = li0 >> 2, c0 = (li0 & 3) * 8;
    int r1 = li1 >> 2, c1 = (li1 & 3) * 8;
    long aoff0 = (long)min(m0 + r0, M - 1) * lda + c0;
    long aoff1 = (long)min(m0 + r1, M - 1) * lda + c1;
    long woff0 = (long)min(n0 + r0, N - 1) * ldw + c0;
    long woff1 = (long)min(n0 + r1, N - 1) * ldw + c1;
    char* AsB0 = (char*)As + wid * 1024;
    char* AsB1 = (char*)As + (4 + wid) * 1024;
    char* BsB0 = (char*)Bs + wid * 1024;
    char* BsB1 = (char*)Bs + (4 + wid) * 1024;

    f32x4 acc[4][4] = {};

    for (int k0 = 0; k0 < K; k0 += 32) {
        __builtin_amdgcn_global_load_lds((glb_u16_t*)(A + aoff0 + k0), (lds_u16_t*)AsB0, 16, 0, 0);
        __builtin_amdgcn_global_load_lds((glb_u16_t*)(A + aoff1 + k0), (lds_u16_t*)AsB1, 16, 0, 0);
        __builtin_amdgcn_global_load_lds((glb_u16_t*)(W + woff0 + k0), (lds_u16_t*)BsB0, 16, 0, 0);
        __builtin_amdgcn_global_load_lds((glb_u16_t*)(W + woff1 + k0), (lds_u16_t*)BsB1, 16, 0, 0);
        __syncthreads();   // compiler drains vmcnt(0) before s_barrier
        bf16x8 af[4], bw[4];
#pragma unroll
        for (int m = 0; m < 4; m++)
            af[m] = *reinterpret_cast<const bf16x8*>(&As[(wr + m * 16 + fr) * 32 + fk]);
#pragma unroll
        for (int n = 0; n < 4; n++)
            bw[n] = *reinterpret_cast<const bf16x8*>(&Bs[(wc + n * 16 + fr) * 32 + fk]);
#pragma unroll
        for (int m = 0; m < 4; m++)
#pragma unroll
            for (int n = 0; n < 4; n++)
                acc[m][n] = __builtin_amdgcn_mfma_f32_16x16x32_bf16(af[m], bw[n], acc[m][n], 0, 0, 0);
        __syncthreads();   // protect LDS before next-iteration overwrite
    }

    // C/D layout: col = lane&15, row = (lane>>4)*4 + reg
    int crow = (lane >> 4) * 4;
#pragma unroll
    for (int m = 0; m < 4; m++) {
#pragma unroll
        for (int n = 0; n < 4; n++) {
            int col = n0 + wc + n * 16 + fr;
            if (col >= N) continue;
            float bv = bias ? bias[col] : 0.f;
            int rbase = m0 + wr + m * 16 + crow;
#pragma unroll
            for (int rr = 0; rr < 4; rr++) {
                int row = rbase + rr;
                if (row >= M) continue;
                float v = acc[m][n][rr] + bv;
                if (RELU) v = fmaxf(v, 0.f);
                long idx = (long)row * ldc + col;
                if (OB) ((u16*)C)[idx] = f2bf(v);
                else    ((float*)C)[idx] = v;
            }
        }
    }
}

// ---------------- bf16 MFMA GEMM 64x64 (batched, for attention): C = A * W^T + bias ----------------
template<int OB, int RELU>
__global__ __launch_bounds__(256) void gemm_bt(
    const u16* __restrict__ A, int lda, long sAb, long sAh,
    const u16* __restrict__ W, int ldw, long sWb, long sWh,
    const float* __restrict__ bias,
    void* __restrict__ C, int ldc, long sCb, long sCh,
    int M, int N, int K, int NH)
{
    __shared__ __align__(16) u16 As[64][40];   // +8 pad: breaks pow2 bank stride
    __shared__ __align__(16) u16 Bs[64][40];
    int z = blockIdx.z, zb = z / NH, zh = z % NH;
    const u16* Ap = A + (long)zb * sAb + (long)zh * sAh;
    const u16* Wp = W + (long)zb * sWb + (long)zh * sWh;
    long coff = (long)zb * sCb + (long)zh * sCh;
    int m0 = blockIdx.y * 64, n0 = blockIdx.x * 64;
    int tid = threadIdx.x;
    int lrow = tid >> 2;              // 0..63
    int lcb = (tid & 3) * 8;          // 0,8,16,24
    int wid = tid >> 6, lane = tid & 63;
    int wr = (wid >> 1) * 32, wc = (wid & 1) * 32;
    int fr = lane & 15, fk = (lane >> 4) * 8;

    f32x4 zero4 = {0.f, 0.f, 0.f, 0.f};
    f32x4 acc00 = zero4, acc01 = zero4, acc10 = zero4, acc11 = zero4;

    int aRow = m0 + lrow; bool aOK = aRow < M;
    int wRow = n0 + lrow; bool wOK = wRow < N;
    const u16* aP = Ap + (long)aRow * lda + lcb;
    const u16* wP = Wp + (long)wRow * ldw + lcb;
    uint4 zz = {0u, 0u, 0u, 0u};

    for (int k0 = 0; k0 < K; k0 += 32) {
        uint4 av = zz, wv = zz;
        if (aOK) av = *reinterpret_cast<const uint4*>(aP + k0);
        if (wOK) wv = *reinterpret_cast<const uint4*>(wP + k0);
        __syncthreads();
        *reinterpret_cast<uint4*>(&As[lrow][lcb]) = av;
        *reinterpret_cast<uint4*>(&Bs[lrow][lcb]) = wv;
        __syncthreads();
        bf16x8 a0 = *reinterpret_cast<const bf16x8*>(&As[wr + fr][fk]);
        bf16x8 a1 = *reinterpret_cast<const bf16x8*>(&As[wr + 16 + fr][fk]);
        bf16x8 b0 = *reinterpret_cast<const bf16x8*>(&Bs[wc + fr][fk]);
        bf16x8 b1 = *reinterpret_cast<const bf16x8*>(&Bs[wc + 16 + fr][fk]);
        acc00 = __builtin_amdgcn_mfma_f32_16x16x32_bf16(a0, b0, acc00, 0, 0, 0);
        acc01 = __builtin_amdgcn_mfma_f32_16x16x32_bf16(a0, b1, acc01, 0, 0, 0);
        acc10 = __builtin_amdgcn_mfma_f32_16x16x32_bf16(a1, b0, acc10, 0, 0, 0);
        acc11 = __builtin_amdgcn_mfma_f32_16x16x32_bf16(a1, b1, acc11, 0, 0, 0);
    }

    int crow = (lane >> 4) * 4;
    f32x4 accs[2][2] = {{acc00, acc01}, {acc10, acc11}};
#pragma unroll
    for (int fm = 0; fm < 2; fm++) {
#pragma unroll
        for (int fn = 0; fn < 2; fn++) {
            int col = n0 + wc + fn * 16 + fr;
            if (col >= N) continue;
            float bv = bias ? bias[col] : 0.f;
#pragma unroll
            for (int rr = 0; rr < 4; rr++) {
                int row = m0 + wr + fm * 16 + crow + rr;
                if (row >= M) continue;
                float v = accs[fm][fn][rr] + bv;
                if (RELU) v = fmaxf(v, 0.f);
                long idx = coff + (long)row * ldc + col;
                if (OB) ((u16*)C)[idx] = f2bf(v);
                else    ((float*)C)[idx] = v;
            }
        }
    }
}

// ---------------- V transpose with zero-pad: VT[z][d][k] = V[k][d], k>=rowsIn -> 0 ----------------
__global__ __launch_bounds__(256) void transpose_pad(
    const u16* __restrict__ V, long sVb, long sVh, int ldv, int NH,
    u16* __restrict__ VT, long sVT, int rowsIn, int Kp)
{
    __shared__ u16 tile[32][33];
    int z = blockIdx.z, zb = z / NH, zh = z % NH;
    const u16* Vp = V + (long)zb * sVb + (long)zh * sVh;
    int k0 = blockIdx.x * 32, d0 = blockIdx.y * 32;
#pragma unroll
    for (int i = 0; i < 4; i++) {
        int k = k0 + threadIdx.y + i * 8;
        int d = d0 + threadIdx.x;
        tile[threadIdx.y + i * 8][threadIdx.x] = (k < rowsIn) ? Vp[(long)k * ldv + d] : (u16)0;
    }
    __syncthreads();
    u16* Op = VT + (long)z * sVT;
#pragma unroll
    for (int i = 0; i < 4; i++) {
        int d = d0 + threadIdx.y + i * 8;
        int k = k0 + threadIdx.x;
        Op[(long)d * Kp + k] = tile[threadIdx.x][threadIdx.y + i * 8];
    }
}

// ---------------- row softmax (optionally causal), f32 scores -> bf16 probs, zero-pad to ld_out ----------------
__global__ __launch_bounds__(256) void softmax_kernel(
    const float* __restrict__ S, u16* __restrict__ P,
    int qrows, int cols_in, int ld_out, float scale, int causal)
{
    __shared__ float red[4];
    int r = blockIdx.x;
    int q = r % qrows;
    const float* srow = S + (long)r * cols_in;
    u16* prow = P + (long)r * ld_out;
    int valid = causal ? (q + 1) : cols_in;
    int tid = threadIdx.x, lane = tid & 63, wid = tid >> 6;
    int c0 = tid, c1 = tid + 256;
    float v0 = -3e38f, v1 = -3e38f;
    if (c0 < valid) v0 = srow[c0] * scale;
    if (c1 < valid) v1 = srow[c1] * scale;
    float mx = fmaxf(v0, v1);
#pragma unroll
    for (int o = 32; o; o >>= 1) mx = fmaxf(mx, __shfl_down(mx, o, 64));
    if (lane == 0) red[wid] = mx;
    __syncthreads();
    mx = fmaxf(fmaxf(red[0], red[1]), fmaxf(red[2], red[3]));
    __syncthreads();
    float e0 = (c0 < valid) ? __expf(v0 - mx) : 0.f;
    float e1 = (c1 < valid) ? __expf(v1 - mx) : 0.f;
    float s = e0 + e1;
#pragma unroll
    for (int o = 32; o; o >>= 1) s += __shfl_down(s, o, 64);
    if (lane == 0) red[wid] = s;
    __syncthreads();
    s = red[0] + red[1] + red[2] + red[3];
    float inv = 1.f / s;
    if (c0 < ld_out) prow[c0] = f2bf(e0 * inv);
    if (c1 < ld_out) prow[c1] = f2bf(e1 * inv);
}

// ---------------- fused residual add + LayerNorm; writes f32 stream + bf16 copy ----------------
__global__ __launch_bounds__(256) void ln_kernel(
    const float* __restrict__ xin, const float* __restrict__ sub,
    const float* __restrict__ g, const float* __restrict__ bta,
    float* __restrict__ xout, u16* __restrict__ xb)
{
    __shared__ float red[4];
    long r = blockIdx.x;
    const float* a = xin + r * 768;
    const float* s2 = sub + r * 768;
    int tid = threadIdx.x, lane = tid & 63, wid = tid >> 6;
    float v[3];
    float sum = 0.f;
#pragma unroll
    for (int j = 0; j < 3; j++) { int d = tid + j * 256; v[j] = a[d] + s2[d]; sum += v[j]; }
#pragma unroll
    for (int o = 32; o; o >>= 1) sum += __shfl_down(sum, o, 64);
    if (lane == 0) red[wid] = sum;
    __syncthreads();
    float mean = (red[0] + red[1] + red[2] + red[3]) * (1.f / 768.f);
    __syncthreads();
    float vs = 0.f;
#pragma unroll
    for (int j = 0; j < 3; j++) { float t = v[j] - mean; vs += t * t; }
#pragma unroll
    for (int o = 32; o; o >>= 1) vs += __shfl_down(vs, o, 64);
    if (lane == 0) red[wid] = vs;
    __syncthreads();
    float var = (red[0] + red[1] + red[2] + red[3]) * (1.f / 768.f);
    float rstd = rsqrtf(var + 1e-5f);
#pragma unroll
    for (int j = 0; j < 3; j++) {
        int d = tid + j * 256;
        float y = (v[j] - mean) * rstd * g[d] + bta[d];
        xout[r * 768 + d] = y;
        xb[r * 768 + d] = f2bf(y);
    }
}

// ---------------- second output: labels[:, 1:] as FLOAT32 (d_out is float*) ----------------
__global__ void labels_out_kernel(const int* __restrict__ labels, float* __restrict__ out) {
    int i = blockIdx.x * 256 + threadIdx.x;
    if (i >= 8192) return;
    int b = i >> 9, t = i & 511;
    out[i] = (float)labels[b * 513 + t + 1];
}

// ---------------- host helpers ----------------
static void gemm_launch(hipStream_t st, bool outbf, bool relu,
    const u16* A, int lda, long sAb, long sAh,
    const u16* W, int ldw, long sWb, long sWh,
    const float* bias, void* C, int ldc, long sCb, long sCh,
    int M, int N, int K, int Z, int NH)
{
    dim3 g((N + 63) / 64, (M + 63) / 64, Z), b(256, 1, 1);
    if (outbf) {
        if (relu) gemm_bt<1,1><<<g,b,0,st>>>(A,lda,sAb,sAh,W,ldw,sWb,sWh,bias,C,ldc,sCb,sCh,M,N,K,NH);
        else      gemm_bt<1,0><<<g,b,0,st>>>(A,lda,sAb,sAh,W,ldw,sWb,sWh,bias,C,ldc,sCb,sCh,M,N,K,NH);
    } else {
        if (relu) gemm_bt<0,1><<<g,b,0,st>>>(A,lda,sAb,sAh,W,ldw,sWb,sWh,bias,C,ldc,sCb,sCh,M,N,K,NH);
        else      gemm_bt<0,0><<<g,b,0,st>>>(A,lda,sAb,sAh,W,ldw,sWb,sWh,bias,C,ldc,sCb,sCh,M,N,K,NH);
    }
}

static void gemm128_launch(hipStream_t st, bool outbf, bool relu,
    const u16* A, int lda, const u16* W, int ldw,
    const float* bias, void* C, int ldc, int M, int N, int K)
{
    dim3 g((N + 127) / 128, (M + 127) / 128, 1), b(256, 1, 1);
    if (outbf) {
        if (relu) gemm128<1,1><<<g,b,0,st>>>(A,lda,W,ldw,bias,C,ldc,M,N,K);
        else      gemm128<1,0><<<g,b,0,st>>>(A,lda,W,ldw,bias,C,ldc,M,N,K);
    } else {
        gemm128<0,0><<<g,b,0,st>>>(A,lda,W,ldw,bias,C,ldc,M,N,K);
    }
}

extern "C" void kernel_launch(void* const* d_in, const int* in_sizes, int n_in,
                              void* d_out, int out_size, void* d_ws, size_t ws_size,
                              hipStream_t stream)
{
    const int*   labels = (const int*)  d_in[0];
    const float* vision = (const float*)d_in[1];
    const float* vpw    = (const float*)d_in[2];
    const float* vpb    = (const float*)d_in[3];
    const float* temb   = (const float*)d_in[4];
    const float* pemb   = (const float*)d_in[5];
    const float* saw    = (const float*)d_in[6];
    const float* sab    = (const float*)d_in[7];
    const float* saow   = (const float*)d_in[8];
    const float* saob   = (const float*)d_in[9];
    const float* caw    = (const float*)d_in[10];
    const float* cab    = (const float*)d_in[11];
    const float* caow   = (const float*)d_in[12];
    const float* caob   = (const float*)d_in[13];
    const float* ln1g   = (const float*)d_in[14];
    const float* ln1b   = (const float*)d_in[15];
    const float* ln2g   = (const float*)d_in[16];
    const float* ln2b   = (const float*)d_in[17];
    const float* ln3g   = (const float*)d_in[18];
    const float* ln3b   = (const float*)d_in[19];
    const float* f1w    = (const float*)d_in[20];
    const float* f1b    = (const float*)d_in[21];
    const float* f2w    = (const float*)d_in[22];
    const float* f2b    = (const float*)d_in[23];
    const float* ow     = (const float*)d_in[24];
    const float* ob     = (const float*)d_in[25];
    (void)in_sizes; (void)n_in; (void)out_size;

    // ---- workspace layout (~291 MB) ----
    char* p = (char*)d_ws;
    auto alloc = [&](long elems, int esz) -> char* {
        char* r = p; p += ((long)elems * esz + 255) & ~255L; return r;
    };
    u16* wb_vp  = (u16*)alloc(768L*768, 2);
    u16* wb_sa  = (u16*)alloc(3L*2304*768, 2);
    u16* wb_sao = (u16*)alloc(3L*768*768, 2);
    u16* wb_ca  = (u16*)alloc(3L*2304*768, 2);
    u16* wb_cao = (u16*)alloc(3L*768*768, 2);
    u16* wb_f1  = (u16*)alloc(3L*1024*768, 2);
    u16* wb_f2  = (u16*)alloc(3L*768*1024, 2);
    u16* wb_ow  = (u16*)alloc(10000L*768, 2);
    u16* vis_b  = (u16*)alloc(3152L*768, 2);
    u16* mem_b  = (u16*)alloc(3152L*768, 2);
    float* x    = (float*)alloc(8192L*768, 4);
    u16* xb     = (u16*)alloc(8192L*768, 2);
    u16* qkv    = (u16*)alloc(8192L*2304, 2);   // reused: {qkv} | {q_bf,kv_bf} | {h_bf}
    u16* q_bf   = qkv;
    u16* kv_bf  = qkv + 8192L*768;
    u16* h_bf   = qkv;
    float* sc   = (float*)alloc(64L*512*512, 4);
    u16* pr     = (u16*)alloc(64L*512*512, 2);
    u16* vt     = (u16*)alloc(64L*192*512, 2);
    u16* attn   = (u16*)alloc(8192L*768, 2);
    float* sub  = (float*)alloc(8192L*768, 4);
    if ((size_t)(p - (char*)d_ws) > ws_size) return;   // clean fail if ws too small

    auto cast = [&](const float* s, u16* d, long n) {
        long n4 = n >> 2;
        int blocks = (int)((n4 + 255) / 256); if (blocks > 4096) blocks = 4096;
        cast_f32_bf16<<<dim3(blocks), dim3(256), 0, stream>>>(s, d, n4);
    };
    cast(vpw,  wb_vp,  768L*768);
    cast(saw,  wb_sa,  3L*2304*768);
    cast(saow, wb_sao, 3L*768*768);
    cast(caw,  wb_ca,  3L*2304*768);
    cast(caow, wb_cao, 3L*768*768);
    cast(f1w,  wb_f1,  3L*1024*768);
    cast(f2w,  wb_f2,  3L*768*1024);
    cast(ow,   wb_ow,  10000L*768);
    cast(vision, vis_b, 3152L*768);

    embed_kernel<<<dim3(8192), dim3(256), 0, stream>>>(labels, temb, pemb, x, xb);

    // mem = vision @ vis_proj_w^T + b   (16*197=3152 rows)
    gemm128_launch(stream, true, false, vis_b, 768, wb_vp, 768, vpb, mem_b, 768, 3152, 768, 768);

    const float scale = 0.07216878364870323f;  // 1/sqrt(192)

    for (int l = 0; l < 3; l++) {
        // ======== self-attention ========
        const u16* Wsa = wb_sa + (long)l*2304*768;
        gemm128_launch(stream, true, false, xb, 768, Wsa, 768, sab + l*2304,
                       qkv, 2304, 8192, 2304, 768);
        transpose_pad<<<dim3(16,6,64), dim3(32,8), 0, stream>>>(
            qkv + 1536, 512L*2304, 192L, 2304, 4, vt, 192L*512, 512, 512);
        // scores = Q K^T  (batched over b,h: z = b*4+h)
        gemm_launch(stream, false, false, qkv, 2304, 512L*2304, 192, qkv + 768, 2304, 512L*2304, 192,
                    nullptr, sc, 512, 4L*512*512, 512L*512, 512, 512, 192, 64, 4);
        softmax_kernel<<<dim3(64*512), dim3(256), 0, stream>>>(sc, pr, 512, 512, 512, scale, 1);
        // O = P @ V  (W = V^T)
        gemm_launch(stream, true, false, pr, 512, 4L*512*512, 512L*512, vt, 512, 4L*192*512, 192L*512,
                    nullptr, attn, 768, 512L*768, 192, 512, 192, 512, 64, 4);
        gemm128_launch(stream, false, false, attn, 768, wb_sao + (long)l*768*768, 768,
                       saob + l*768, sub, 768, 8192, 768, 768);
        ln_kernel<<<dim3(8192), dim3(256), 0, stream>>>(x, sub, ln1g + l*768, ln1b + l*768, x, xb);

        // ======== cross-attention ========
        const u16* Wca = wb_ca + (long)l*2304*768;
        gemm128_launch(stream, true, false, xb, 768, Wca, 768, cab + l*2304,
                       q_bf, 768, 8192, 768, 768);
        gemm128_launch(stream, true, false, mem_b, 768, Wca + 768L*768, 768, cab + l*2304 + 768,
                       kv_bf, 1536, 3152, 1536, 768);
        transpose_pad<<<dim3(7,6,64), dim3(32,8), 0, stream>>>(
            kv_bf + 768, 197L*1536, 192L, 1536, 4, vt, 192L*224, 197, 224);
        gemm_launch(stream, false, false, q_bf, 768, 512L*768, 192, kv_bf, 1536, 197L*1536, 192,
                    nullptr, sc, 197, 4L*512*197, 512L*197, 512, 197, 192, 64, 4);
        softmax_kernel<<<dim3(64*512), dim3(256), 0, stream>>>(sc, pr, 512, 197, 224, scale, 0);
        gemm_launch(stream, true, false, pr, 224, 4L*512*224, 512L*224, vt, 224, 4L*192*224, 192L*224,
                    nullptr, attn, 768, 512L*768, 192, 512, 192, 224, 64, 4);
        gemm128_launch(stream, false, false, attn, 768, wb_cao + (long)l*768*768, 768,
                       caob + l*768, sub, 768, 8192, 768, 768);
        ln_kernel<<<dim3(8192), dim3(256), 0, stream>>>(x, sub, ln2g + l*768, ln2b + l*768, x, xb);

        // ======== feed-forward ========
        gemm128_launch(stream, true, true, xb, 768, wb_f1 + (long)l*1024*768, 768,
                       f1b + l*1024, h_bf, 1024, 8192, 1024, 768);
        gemm128_launch(stream, false, false, h_bf, 1024, wb_f2 + (long)l*768*1024, 1024,
                       f2b + l*768, sub, 768, 8192, 768, 1024);
        ln_kernel<<<dim3(8192), dim3(256), 0, stream>>>(x, sub, ln3g + l*768, ln3b + l*768, x, xb);
    }

    // vocab head -> d_out (FLOAT32 logits — d_out is float*)
    gemm128_launch(stream, false, false, xb, 768, wb_ow, 768, ob,
                   (float*)d_out, 10000, 8192, 10000, 768);
    // second output: labels[:, 1:] as float32
    labels_out_kernel<<<dim3(32), dim3(256), 0, stream>>>(labels, (float*)d_out + 81920000L);
}

// Round 4
// 1663.226 us; speedup vs baseline: 1.1422x; 1.1150x over previous
//
#include <hip/hip_runtime.h>

typedef unsigned short u16;
typedef __bf16 bf16x8 __attribute__((ext_vector_type(8)));
typedef float f32x4 __attribute__((ext_vector_type(4)));

typedef __attribute__((address_space(3))) u16 lds_u16_t;
typedef __attribute__((address_space(1))) const u16 glb_u16_t;

__device__ __forceinline__ u16 f2bf(float f) {
    union { float f; unsigned u; } v; v.f = f;
    unsigned r = v.u + 0x7FFFu + ((v.u >> 16) & 1u);   // RNE
    return (u16)(r >> 16);
}
__device__ __forceinline__ float bf2f(u16 h) {
    union { unsigned u; float f; } v; v.u = ((unsigned)h) << 16; return v.f;
}

// ---------------- f32 -> bf16 cast (n % 4 == 0) ----------------
__global__ void cast_f32_bf16(const float* __restrict__ src, u16* __restrict__ dst, long n4) {
    long i = (long)blockIdx.x * blockDim.x + threadIdx.x;
    long stride = (long)gridDim.x * blockDim.x;
    for (; i < n4; i += stride) {
        float4 f = reinterpret_cast<const float4*>(src)[i];
        ushort4 o;
        o.x = f2bf(f.x); o.y = f2bf(f.y); o.z = f2bf(f.z); o.w = f2bf(f.w);
        reinterpret_cast<ushort4*>(dst)[i] = o;
    }
}

// ---------------- token + positional embedding ----------------
__global__ __launch_bounds__(256) void embed_kernel(
    const int* __restrict__ labels, const float* __restrict__ tok_emb,
    const float* __restrict__ pos_emb, float* __restrict__ x, u16* __restrict__ xb)
{
    int r = blockIdx.x;                 // 0..8191 = b*512+t
    int b = r >> 9, t = r & 511;
    int tok = labels[b * 513 + t];      // labels[:, :-1]
    const float* te = tok_emb + (long)tok * 768;
    const float* pe = pos_emb + (long)t * 768;
    float* xo  = x  + (long)r * 768;
    u16*   xo2 = xb + (long)r * 768;
#pragma unroll
    for (int j = 0; j < 3; j++) {
        int d = threadIdx.x + j * 256;
        float v = te[d] + pe[d];
        xo[d] = v;
        xo2[d] = f2bf(v);
    }
}

// ================= 128x128 MFMA GEMM, 2-phase double-buffered (T3-minimum) =================
// C = A[M,K] * W[N,K]^T + bias. 4 waves (2x2), each wave 64x64 = 4x4 16x16x32 frags.
// global_load_lds width=16 into linear LDS [128][32] per buffer; stage(t+1) issued BEFORE
// compute(t); one __syncthreads per K-step (drains vmcnt -> next buffer ready).
// Bijective XCD swizzle (m204). Row-clamped edges. K % 64 == 0 here (768/1024).
template<int OB, int RELU>
__global__ __launch_bounds__(256) void gemm128(
    const u16* __restrict__ A, int lda,
    const u16* __restrict__ W, int ldw,
    const float* __restrict__ bias,
    void* __restrict__ C, int ldc,
    int M, int N, int K)
{
    __shared__ __align__(16) u16 As0[128 * 32];
    __shared__ __align__(16) u16 As1[128 * 32];
    __shared__ __align__(16) u16 Bs0[128 * 32];
    __shared__ __align__(16) u16 Bs1[128 * 32];

    // ---- bijective XCD swizzle: contiguous work chunk per XCD (m204) ----
    int nwg = (int)(gridDim.x * gridDim.y);
    int orig = (int)(blockIdx.y * gridDim.x + blockIdx.x);
    int q = nwg >> 3, r = nwg & 7;
    int xcd = orig & 7, loc = orig >> 3;
    int wg = (xcd < r ? xcd * (q + 1) : r * (q + 1) + (xcd - r) * q) + loc;
    int bx = wg % (int)gridDim.x, by = wg / (int)gridDim.x;

    int m0 = by * 128, n0 = bx * 128;
    int tid = threadIdx.x, wid = tid >> 6, lane = tid & 63;
    int wr = (wid >> 1) * 64, wc = (wid & 1) * 64;
    int fr = lane & 15, fk = (lane >> 4) * 8;

    // staging geometry: 8 KB/tile = 512 x 16B; thread li stages 2 chunks (li, li+256)
    int li0 = wid * 64 + lane;
    int li1 = li0 + 256;
    int r0 = li0 >> 2, c0 = (li0 & 3) * 8;
    int r1 = li1 >> 2, c1 = (li1 & 3) * 8;
    long aoff0 = (long)min(m0 + r0, M - 1) * lda + c0;
    long aoff1 = (long)min(m0 + r1, M - 1) * lda + c1;
    long woff0 = (long)min(n0 + r0, N - 1) * ldw + c0;
    long woff1 = (long)min(n0 + r1, N - 1) * ldw + c1;
    char* a0base = (char*)As0 + wid * 1024;
    char* a1base = (char*)As1 + wid * 1024;
    char* b0base = (char*)Bs0 + wid * 1024;
    char* b1base = (char*)Bs1 + wid * 1024;

    f32x4 acc[4][4] = {};

    auto stage = [&](char* ab, char* bb, int k0) {
        __builtin_amdgcn_global_load_lds((glb_u16_t*)(A + aoff0 + k0), (lds_u16_t*)ab, 16, 0, 0);
        __builtin_amdgcn_global_load_lds((glb_u16_t*)(A + aoff1 + k0), (lds_u16_t*)(ab + 4096), 16, 0, 0);
        __builtin_amdgcn_global_load_lds((glb_u16_t*)(W + woff0 + k0), (lds_u16_t*)bb, 16, 0, 0);
        __builtin_amdgcn_global_load_lds((glb_u16_t*)(W + woff1 + k0), (lds_u16_t*)(bb + 4096), 16, 0, 0);
    };
    auto compute = [&](const u16* as, const u16* bs) {
        bf16x8 af[4], bw[4];
#pragma unroll
        for (int m = 0; m < 4; m++)
            af[m] = *reinterpret_cast<const bf16x8*>(&as[(wr + m * 16 + fr) * 32 + fk]);
#pragma unroll
        for (int n = 0; n < 4; n++)
            bw[n] = *reinterpret_cast<const bf16x8*>(&bs[(wc + n * 16 + fr) * 32 + fk]);
#pragma unroll
        for (int m = 0; m < 4; m++)
#pragma unroll
            for (int n = 0; n < 4; n++)
                acc[m][n] = __builtin_amdgcn_mfma_f32_16x16x32_bf16(af[m], bw[n], acc[m][n], 0, 0, 0);
    };

    int nt = K >> 5;                       // even for K in {768, 1024}
    stage(a0base, b0base, 0);
    __syncthreads();                       // buf0 ready
    for (int t = 0; t < nt; t += 2) {
        if (t + 1 < nt) stage(a1base, b1base, (t + 1) * 32);   // prefetch into buf1
        compute(As0, Bs0);
        __syncthreads();                   // buf1 ready; buf0 reads retired
        if (t + 2 < nt) stage(a0base, b0base, (t + 2) * 32);   // prefetch into buf0
        compute(As1, Bs1);
        __syncthreads();                   // buf0 ready; buf1 reads retired
    }

    // C/D layout: col = lane&15, row = (lane>>4)*4 + reg
    int crow = (lane >> 4) * 4;
#pragma unroll
    for (int m = 0; m < 4; m++) {
#pragma unroll
        for (int n = 0; n < 4; n++) {
            int col = n0 + wc + n * 16 + fr;
            if (col >= N) continue;
            float bv = bias ? bias[col] : 0.f;
            int rbase = m0 + wr + m * 16 + crow;
#pragma unroll
            for (int rr = 0; rr < 4; rr++) {
                int row = rbase + rr;
                if (row >= M) continue;
                float v = acc[m][n][rr] + bv;
                if (RELU) v = fmaxf(v, 0.f);
                long idx = (long)row * ldc + col;
                if (OB) ((u16*)C)[idx] = f2bf(v);
                else    ((float*)C)[idx] = v;
            }
        }
    }
}

// ---------------- bf16 MFMA GEMM 64x64 (batched, for attention): C = A * W^T + bias ----------------
template<int OB, int RELU>
__global__ __launch_bounds__(256) void gemm_bt(
    const u16* __restrict__ A, int lda, long sAb, long sAh,
    const u16* __restrict__ W, int ldw, long sWb, long sWh,
    const float* __restrict__ bias,
    void* __restrict__ C, int ldc, long sCb, long sCh,
    int M, int N, int K, int NH)
{
    __shared__ __align__(16) u16 As[64][40];   // +8 pad: breaks pow2 bank stride
    __shared__ __align__(16) u16 Bs[64][40];
    int z = blockIdx.z, zb = z / NH, zh = z % NH;
    const u16* Ap = A + (long)zb * sAb + (long)zh * sAh;
    const u16* Wp = W + (long)zb * sWb + (long)zh * sWh;
    long coff = (long)zb * sCb + (long)zh * sCh;
    int m0 = blockIdx.y * 64, n0 = blockIdx.x * 64;
    int tid = threadIdx.x;
    int lrow = tid >> 2;              // 0..63
    int lcb = (tid & 3) * 8;          // 0,8,16,24
    int wid = tid >> 6, lane = tid & 63;
    int wr = (wid >> 1) * 32, wc = (wid & 1) * 32;
    int fr = lane & 15, fk = (lane >> 4) * 8;

    f32x4 zero4 = {0.f, 0.f, 0.f, 0.f};
    f32x4 acc00 = zero4, acc01 = zero4, acc10 = zero4, acc11 = zero4;

    int aRow = m0 + lrow; bool aOK = aRow < M;
    int wRow = n0 + lrow; bool wOK = wRow < N;
    const u16* aP = Ap + (long)aRow * lda + lcb;
    const u16* wP = Wp + (long)wRow * ldw + lcb;
    uint4 zz = {0u, 0u, 0u, 0u};

    for (int k0 = 0; k0 < K; k0 += 32) {
        uint4 av = zz, wv = zz;
        if (aOK) av = *reinterpret_cast<const uint4*>(aP + k0);
        if (wOK) wv = *reinterpret_cast<const uint4*>(wP + k0);
        __syncthreads();
        *reinterpret_cast<uint4*>(&As[lrow][lcb]) = av;
        *reinterpret_cast<uint4*>(&Bs[lrow][lcb]) = wv;
        __syncthreads();
        bf16x8 a0 = *reinterpret_cast<const bf16x8*>(&As[wr + fr][fk]);
        bf16x8 a1 = *reinterpret_cast<const bf16x8*>(&As[wr + 16 + fr][fk]);
        bf16x8 b0 = *reinterpret_cast<const bf16x8*>(&Bs[wc + fr][fk]);
        bf16x8 b1 = *reinterpret_cast<const bf16x8*>(&Bs[wc + 16 + fr][fk]);
        acc00 = __builtin_amdgcn_mfma_f32_16x16x32_bf16(a0, b0, acc00, 0, 0, 0);
        acc01 = __builtin_amdgcn_mfma_f32_16x16x32_bf16(a0, b1, acc01, 0, 0, 0);
        acc10 = __builtin_amdgcn_mfma_f32_16x16x32_bf16(a1, b0, acc10, 0, 0, 0);
        acc11 = __builtin_amdgcn_mfma_f32_16x16x32_bf16(a1, b1, acc11, 0, 0, 0);
    }

    int crow = (lane >> 4) * 4;
    f32x4 accs[2][2] = {{acc00, acc01}, {acc10, acc11}};
#pragma unroll
    for (int fm = 0; fm < 2; fm++) {
#pragma unroll
        for (int fn = 0; fn < 2; fn++) {
            int col = n0 + wc + fn * 16 + fr;
            if (col >= N) continue;
            float bv = bias ? bias[col] : 0.f;
#pragma unroll
            for (int rr = 0; rr < 4; rr++) {
                int row = m0 + wr + fm * 16 + crow + rr;
                if (row >= M) continue;
                float v = accs[fm][fn][rr] + bv;
                if (RELU) v = fmaxf(v, 0.f);
                long idx = coff + (long)row * ldc + col;
                if (OB) ((u16*)C)[idx] = f2bf(v);
                else    ((float*)C)[idx] = v;
            }
        }
    }
}

// ---------------- V transpose with zero-pad: VT[z][d][k] = V[k][d], k>=rowsIn -> 0 ----------------
__global__ __launch_bounds__(256) void transpose_pad(
    const u16* __restrict__ V, long sVb, long sVh, int ldv, int NH,
    u16* __restrict__ VT, long sVT, int rowsIn, int Kp)
{
    __shared__ u16 tile[32][33];
    int z = blockIdx.z, zb = z / NH, zh = z % NH;
    const u16* Vp = V + (long)zb * sVb + (long)zh * sVh;
    int k0 = blockIdx.x * 32, d0 = blockIdx.y * 32;
#pragma unroll
    for (int i = 0; i < 4; i++) {
        int k = k0 + threadIdx.y + i * 8;
        int d = d0 + threadIdx.x;
        tile[threadIdx.y + i * 8][threadIdx.x] = (k < rowsIn) ? Vp[(long)k * ldv + d] : (u16)0;
    }
    __syncthreads();
    u16* Op = VT + (long)z * sVT;
#pragma unroll
    for (int i = 0; i < 4; i++) {
        int d = d0 + threadIdx.y + i * 8;
        int k = k0 + threadIdx.x;
        Op[(long)d * Kp + k] = tile[threadIdx.x][threadIdx.y + i * 8];
    }
}

// ---------------- row softmax (optionally causal), bf16 scores -> bf16 probs, zero-pad to ld_out ----------------
__global__ __launch_bounds__(256) void softmax_kernel(
    const u16* __restrict__ S, u16* __restrict__ P,
    int qrows, int cols_in, int ld_out, float scale, int causal)
{
    __shared__ float red[4];
    int r = blockIdx.x;
    int q = r % qrows;
    const u16* srow = S + (long)r * cols_in;
    u16* prow = P + (long)r * ld_out;
    int valid = causal ? (q + 1) : cols_in;
    int tid = threadIdx.x, lane = tid & 63, wid = tid >> 6;
    int c0 = tid, c1 = tid + 256;
    float v0 = -3e38f, v1 = -3e38f;
    if (c0 < valid) v0 = bf2f(srow[c0]) * scale;
    if (c1 < valid) v1 = bf2f(srow[c1]) * scale;
    float mx = fmaxf(v0, v1);
#pragma unroll
    for (int o = 32; o; o >>= 1) mx = fmaxf(mx, __shfl_down(mx, o, 64));
    if (lane == 0) red[wid] = mx;
    __syncthreads();
    mx = fmaxf(fmaxf(red[0], red[1]), fmaxf(red[2], red[3]));
    __syncthreads();
    float e0 = (c0 < valid) ? __expf(v0 - mx) : 0.f;
    float e1 = (c1 < valid) ? __expf(v1 - mx) : 0.f;
    float s = e0 + e1;
#pragma unroll
    for (int o = 32; o; o >>= 1) s += __shfl_down(s, o, 64);
    if (lane == 0) red[wid] = s;
    __syncthreads();
    s = red[0] + red[1] + red[2] + red[3];
    float inv = 1.f / s;
    if (c0 < ld_out) prow[c0] = f2bf(e0 * inv);
    if (c1 < ld_out) prow[c1] = f2bf(e1 * inv);
}

// ---------------- fused residual add + LayerNorm; writes f32 stream + bf16 copy ----------------
__global__ __launch_bounds__(256) void ln_kernel(
    const float* __restrict__ xin, const float* __restrict__ sub,
    const float* __restrict__ g, const float* __restrict__ bta,
    float* __restrict__ xout, u16* __restrict__ xb)
{
    __shared__ float red[4];
    long r = blockIdx.x;
    const float* a = xin + r * 768;
    const float* s2 = sub + r * 768;
    int tid = threadIdx.x, lane = tid & 63, wid = tid >> 6;
    float v[3];
    float sum = 0.f;
#pragma unroll
    for (int j = 0; j < 3; j++) { int d = tid + j * 256; v[j] = a[d] + s2[d]; sum += v[j]; }
#pragma unroll
    for (int o = 32; o; o >>= 1) sum += __shfl_down(sum, o, 64);
    if (lane == 0) red[wid] = sum;
    __syncthreads();
    float mean = (red[0] + red[1] + red[2] + red[3]) * (1.f / 768.f);
    __syncthreads();
    float vs = 0.f;
#pragma unroll
    for (int j = 0; j < 3; j++) { float t = v[j] - mean; vs += t * t; }
#pragma unroll
    for (int o = 32; o; o >>= 1) vs += __shfl_down(vs, o, 64);
    if (lane == 0) red[wid] = vs;
    __syncthreads();
    float var = (red[0] + red[1] + red[2] + red[3]) * (1.f / 768.f);
    float rstd = rsqrtf(var + 1e-5f);
#pragma unroll
    for (int j = 0; j < 3; j++) {
        int d = tid + j * 256;
        float y = (v[j] - mean) * rstd * g[d] + bta[d];
        xout[r * 768 + d] = y;
        xb[r * 768 + d] = f2bf(y);
    }
}

// ---------------- second output: labels[:, 1:] as FLOAT32 (d_out is float*) ----------------
__global__ void labels_out_kernel(const int* __restrict__ labels, float* __restrict__ out) {
    int i = blockIdx.x * 256 + threadIdx.x;
    if (i >= 8192) return;
    int b = i >> 9, t = i & 511;
    out[i] = (float)labels[b * 513 + t + 1];
}

// ---------------- host helpers ----------------
static void gemm_launch(hipStream_t st, bool outbf, bool relu,
    const u16* A, int lda, long sAb, long sAh,
    const u16* W, int ldw, long sWb, long sWh,
    const float* bias, void* C, int ldc, long sCb, long sCh,
    int M, int N, int K, int Z, int NH)
{
    dim3 g((N + 63) / 64, (M + 63) / 64, Z), b(256, 1, 1);
    if (outbf) {
        if (relu) gemm_bt<1,1><<<g,b,0,st>>>(A,lda,sAb,sAh,W,ldw,sWb,sWh,bias,C,ldc,sCb,sCh,M,N,K,NH);
        else      gemm_bt<1,0><<<g,b,0,st>>>(A,lda,sAb,sAh,W,ldw,sWb,sWh,bias,C,ldc,sCb,sCh,M,N,K,NH);
    } else {
        if (relu) gemm_bt<0,1><<<g,b,0,st>>>(A,lda,sAb,sAh,W,ldw,sWb,sWh,bias,C,ldc,sCb,sCh,M,N,K,NH);
        else      gemm_bt<0,0><<<g,b,0,st>>>(A,lda,sAb,sAh,W,ldw,sWb,sWh,bias,C,ldc,sCb,sCh,M,N,K,NH);
    }
}

static void gemm128_launch(hipStream_t st, bool outbf, bool relu,
    const u16* A, int lda, const u16* W, int ldw,
    const float* bias, void* C, int ldc, int M, int N, int K)
{
    dim3 g((N + 127) / 128, (M + 127) / 128, 1), b(256, 1, 1);
    if (outbf) {
        if (relu) gemm128<1,1><<<g,b,0,st>>>(A,lda,W,ldw,bias,C,ldc,M,N,K);
        else      gemm128<1,0><<<g,b,0,st>>>(A,lda,W,ldw,bias,C,ldc,M,N,K);
    } else {
        gemm128<0,0><<<g,b,0,st>>>(A,lda,W,ldw,bias,C,ldc,M,N,K);
    }
}

extern "C" void kernel_launch(void* const* d_in, const int* in_sizes, int n_in,
                              void* d_out, int out_size, void* d_ws, size_t ws_size,
                              hipStream_t stream)
{
    const int*   labels = (const int*)  d_in[0];
    const float* vision = (const float*)d_in[1];
    const float* vpw    = (const float*)d_in[2];
    const float* vpb    = (const float*)d_in[3];
    const float* temb   = (const float*)d_in[4];
    const float* pemb   = (const float*)d_in[5];
    const float* saw    = (const float*)d_in[6];
    const float* sab    = (const float*)d_in[7];
    const float* saow   = (const float*)d_in[8];
    const float* saob   = (const float*)d_in[9];
    const float* caw    = (const float*)d_in[10];
    const float* cab    = (const float*)d_in[11];
    const float* caow   = (const float*)d_in[12];
    const float* caob   = (const float*)d_in[13];
    const float* ln1g   = (const float*)d_in[14];
    const float* ln1b   = (const float*)d_in[15];
    const float* ln2g   = (const float*)d_in[16];
    const float* ln2b   = (const float*)d_in[17];
    const float* ln3g   = (const float*)d_in[18];
    const float* ln3b   = (const float*)d_in[19];
    const float* f1w    = (const float*)d_in[20];
    const float* f1b    = (const float*)d_in[21];
    const float* f2w    = (const float*)d_in[22];
    const float* f2b    = (const float*)d_in[23];
    const float* ow     = (const float*)d_in[24];
    const float* ob     = (const float*)d_in[25];
    (void)in_sizes; (void)n_in; (void)out_size;

    // ---- workspace layout ----
    char* p = (char*)d_ws;
    auto alloc = [&](long elems, int esz) -> char* {
        char* r = p; p += ((long)elems * esz + 255) & ~255L; return r;
    };
    u16* wb_vp  = (u16*)alloc(768L*768, 2);
    u16* wb_sa  = (u16*)alloc(3L*2304*768, 2);
    u16* wb_sao = (u16*)alloc(3L*768*768, 2);
    u16* wb_ca  = (u16*)alloc(3L*2304*768, 2);
    u16* wb_cao = (u16*)alloc(3L*768*768, 2);
    u16* wb_f1  = (u16*)alloc(3L*1024*768, 2);
    u16* wb_f2  = (u16*)alloc(3L*768*1024, 2);
    u16* wb_ow  = (u16*)alloc(10000L*768, 2);
    u16* vis_b  = (u16*)alloc(3152L*768, 2);
    u16* mem_b  = (u16*)alloc(3152L*768, 2);
    float* x    = (float*)alloc(8192L*768, 4);
    u16* xb     = (u16*)alloc(8192L*768, 2);
    u16* qkv    = (u16*)alloc(8192L*2304, 2);   // reused: {qkv} | {q_bf,kv_bf} | {h_bf}
    u16* q_bf   = qkv;
    u16* kv_bf  = qkv + 8192L*768;
    u16* h_bf   = qkv;
    u16* scb    = (u16*)alloc(64L*512*512, 2);  // bf16 scores
    u16* pr     = (u16*)alloc(64L*512*512, 2);
    u16* vt     = (u16*)alloc(64L*192*512, 2);
    u16* attn   = (u16*)alloc(8192L*768, 2);
    float* sub  = (float*)alloc(8192L*768, 4);
    if ((size_t)(p - (char*)d_ws) > ws_size) return;   // clean fail if ws too small

    auto cast = [&](const float* s, u16* d, long n) {
        long n4 = n >> 2;
        int blocks = (int)((n4 + 255) / 256); if (blocks > 4096) blocks = 4096;
        cast_f32_bf16<<<dim3(blocks), dim3(256), 0, stream>>>(s, d, n4);
    };
    cast(vpw,  wb_vp,  768L*768);
    cast(saw,  wb_sa,  3L*2304*768);
    cast(saow, wb_sao, 3L*768*768);
    cast(caw,  wb_ca,  3L*2304*768);
    cast(caow, wb_cao, 3L*768*768);
    cast(f1w,  wb_f1,  3L*1024*768);
    cast(f2w,  wb_f2,  3L*768*1024);
    cast(ow,   wb_ow,  10000L*768);
    cast(vision, vis_b, 3152L*768);

    embed_kernel<<<dim3(8192), dim3(256), 0, stream>>>(labels, temb, pemb, x, xb);

    // mem = vision @ vis_proj_w^T + b   (16*197=3152 rows)
    gemm128_launch(stream, true, false, vis_b, 768, wb_vp, 768, vpb, mem_b, 768, 3152, 768, 768);

    const float scale = 0.07216878364870323f;  // 1/sqrt(192)

    for (int l = 0; l < 3; l++) {
        // ======== self-attention ========
        const u16* Wsa = wb_sa + (long)l*2304*768;
        gemm128_launch(stream, true, false, xb, 768, Wsa, 768, sab + l*2304,
                       qkv, 2304, 8192, 2304, 768);
        transpose_pad<<<dim3(16,6,64), dim3(32,8), 0, stream>>>(
            qkv + 1536, 512L*2304, 192L, 2304, 4, vt, 192L*512, 512, 512);
        // scores = Q K^T  (bf16 out; batched over b,h: z = b*4+h)
        gemm_launch(stream, true, false, qkv, 2304, 512L*2304, 192, qkv + 768, 2304, 512L*2304, 192,
                    nullptr, scb, 512, 4L*512*512, 512L*512, 512, 512, 192, 64, 4);
        softmax_kernel<<<dim3(64*512), dim3(256), 0, stream>>>(scb, pr, 512, 512, 512, scale, 1);
        // O = P @ V  (W = V^T)
        gemm_launch(stream, true, false, pr, 512, 4L*512*512, 512L*512, vt, 512, 4L*192*512, 192L*512,
                    nullptr, attn, 768, 512L*768, 192, 512, 192, 512, 64, 4);
        gemm128_launch(stream, false, false, attn, 768, wb_sao + (long)l*768*768, 768,
                       saob + l*768, sub, 768, 8192, 768, 768);
        ln_kernel<<<dim3(8192), dim3(256), 0, stream>>>(x, sub, ln1g + l*768, ln1b + l*768, x, xb);

        // ======== cross-attention ========
        const u16* Wca = wb_ca + (long)l*2304*768;
        gemm128_launch(stream, true, false, xb, 768, Wca, 768, cab + l*2304,
                       q_bf, 768, 8192, 768, 768);
        gemm128_launch(stream, true, false, mem_b, 768, Wca + 768L*768, 768, cab + l*2304 + 768,
                       kv_bf, 1536, 3152, 1536, 768);
        transpose_pad<<<dim3(7,6,64), dim3(32,8), 0, stream>>>(
            kv_bf + 768, 197L*1536, 192L, 1536, 4, vt, 192L*224, 197, 224);
        gemm_launch(stream, true, false, q_bf, 768, 512L*768, 192, kv_bf, 1536, 197L*1536, 192,
                    nullptr, scb, 197, 4L*512*197, 512L*197, 512, 197, 192, 64, 4);
        softmax_kernel<<<dim3(64*512), dim3(256), 0, stream>>>(scb, pr, 512, 197, 224, scale, 0);
        gemm_launch(stream, true, false, pr, 224, 4L*512*224, 512L*224, vt, 224, 4L*192*224, 192L*224,
                    nullptr, attn, 768, 512L*768, 192, 512, 192, 224, 64, 4);
        gemm128_launch(stream, false, false, attn, 768, wb_cao + (long)l*768*768, 768,
                       caob + l*768, sub, 768, 8192, 768, 768);
        ln_kernel<<<dim3(8192), dim3(256), 0, stream>>>(x, sub, ln2g + l*768, ln2b + l*768, x, xb);

        // ======== feed-forward ========
        gemm128_launch(stream, true, true, xb, 768, wb_f1 + (long)l*1024*768, 768,
                       f1b + l*1024, h_bf, 1024, 8192, 1024, 768);
        gemm128_launch(stream, false, false, h_bf, 1024, wb_f2 + (long)l*768*1024, 1024,
                       f2b + l*768, sub, 768, 8192, 768, 1024);
        ln_kernel<<<dim3(8192), dim3(256), 0, stream>>>(x, sub, ln3g + l*768, ln3b + l*768, x, xb);
    }

    // vocab head -> d_out (FLOAT32 logits — d_out is float*)
    gemm128_launch(stream, false, false, xb, 768, wb_ow, 768, ob,
                   (float*)d_out, 10000, 8192, 10000, 768);
    // second output: labels[:, 1:] as float32
    labels_out_kernel<<<dim3(32), dim3(256), 0, stream>>>(labels, (float*)d_out + 81920000L);
}